// Round 12
// baseline (99.270 us; speedup 1.0000x reference)
//
#include <hip/hip_runtime.h>
#include <math.h>

#define H_ 128
#define W_ 128
#define C_ 64
#define B_ 8
#define HW 16384          // H_*W_
#define NPIX (B_*HW)      // 131072

typedef __attribute__((ext_vector_type(8))) short short8;
typedef __attribute__((ext_vector_type(4))) float f32x4;

__device__ __forceinline__ float softplus_fast(float v) {
    return fmaxf(v, 0.f) + __logf(1.f + __expf(-fabsf(v)));
}

__device__ __forceinline__ unsigned short f2bf(float f) {
    unsigned u = __builtin_bit_cast(unsigned, f);
    unsigned r = (u + 0x7fffu + ((u >> 16) & 1u)) >> 16;
    return (unsigned short)r;
}

// async global->LDS, 16B per lane. LDS dest must be linear: base + lane*16.
__device__ __forceinline__ void gl_lds16(const float* g, float* l) {
    __builtin_amdgcn_global_load_lds(
        (const __attribute__((address_space(1))) void*)g,
        (__attribute__((address_space(3))) void*)l, 16, 0, 0);
}

// K0: (a) w2 -> bf16 A-frags (wtr); (b) w_reduce -> A-frags (wtr1);
//     (c) w_span -> 2 zero-padded A-frags (wtr2); (d) block 0 zeroes
//     stats[128] + zgz[128] (must run every call; stats accumulate).
__global__ __launch_bounds__(256) void k0_wtr(const float* __restrict__ w2,
                                              const float* __restrict__ wr,
                                              const float* __restrict__ wspan,
                                              unsigned short* __restrict__ wtr,
                                              unsigned short* __restrict__ wtr1,
                                              unsigned short* __restrict__ wtr2,
                                              float* __restrict__ stats)
{
    int t = blockIdx.x * 256 + threadIdx.x;
    if (t < 256) stats[t] = 0.f;            // stats[128] + zeros[128]
    if (t < 512) {
        int lane = t & 63, f = t >> 6;
        int mt = f >> 1, kh = f & 1;
        int o  = mt * 16 + (lane & 15);
        int c0 = kh * 32 + ((lane >> 4) << 3);
        uint4 pk;
        unsigned short* pv = (unsigned short*)&pk;
#pragma unroll
        for (int e = 0; e < 8; ++e)
            pv[e] = f2bf(wr[o * C_ + c0 + e]);
        *(uint4*)&wtr1[(size_t)t * 8] = pk;
    } else if (t < 640) {
        int tt = t - 512;
        int lane = tt & 63, kh = tt >> 6;
        int o  = lane & 15;
        int c0 = (kh << 5) + ((lane >> 4) << 3);
        uint4 pk;
        unsigned short* pv = (unsigned short*)&pk;
#pragma unroll
        for (int e = 0; e < 8; ++e)
            pv[e] = (o < 9) ? f2bf(wspan[o * C_ + c0 + e]) : (unsigned short)0;
        *(uint4*)&wtr2[(size_t)tt * 8] = pk;
    }
    if (t >= 4 * 18 * 64) return;
    int lane = t & 63;
    int f    = (t >> 6) % 18;
    int wv   = t / (18 * 64);
    int koff = f >> 1, ch = f & 1;
    int o = wv * 16 + (lane & 15);
    int cb = ch * 32 + ((lane >> 4) << 3);
    uint4 pk;
    unsigned short* pv = (unsigned short*)&pk;
#pragma unroll
    for (int e = 0; e < 8; ++e)
        pv[e] = f2bf(w2[(size_t)o * 576 + (size_t)(cb + e) * 9 + koff]);
    *(uint4*)&wtr[(size_t)t * 8] = pk;
}

// K1: r = W_reduce @ x + b_reduce via MFMA implicit GEMM; BN stats
// (sum/sumsq incl. bias, f32) folded in from the accumulators. Unchanged.
__global__ __launch_bounds__(256) void k1_mfma(
    const float* __restrict__ x, const unsigned short* __restrict__ wtr1,
    const float* __restrict__ br, unsigned short* __restrict__ rb,
    float* __restrict__ stats)
{
    __shared__ unsigned short xb[256 * 64];   // 32KB, chunk-XOR swizzled
    __shared__ float brs[C_];
    __shared__ float ls[128];
    int tid = threadIdx.x;
    int blk = blockIdx.x;
    int pid0 = blk << 8;
    int b    = pid0 >> 14;
    int rem0 = pid0 & (HW - 1);
    const float* xbase = x + (((size_t)b * C_) << 14) + rem0;

    if (tid < C_) brs[tid] = br[tid];
    if (tid < 128) ls[tid] = 0.f;

    int p = tid;
#pragma unroll
    for (int m = 0; m < 8; ++m) {
        float tmp[8];
#pragma unroll
        for (int e = 0; e < 8; ++e)
            tmp[e] = xbase[((size_t)(m * 8 + e) << 14) + p];
        unsigned pk[4];
#pragma unroll
        for (int e = 0; e < 4; ++e)
            pk[e] = (unsigned)f2bf(tmp[2 * e]) | ((unsigned)f2bf(tmp[2 * e + 1]) << 16);
        *(uint4*)&xb[(p << 6) + ((m ^ (p & 7)) << 3)] = *(uint4*)pk;
    }

    int wid = tid >> 6, lane = tid & 63;
    int nl  = lane & 15;
    int kg  = lane >> 4;

    short8 af[8];
    const short8* wp = (const short8*)wtr1;
#pragma unroll
    for (int f = 0; f < 8; ++f) af[f] = wp[f * 64 + lane];

    f32x4 acc[4][4];
#pragma unroll
    for (int mt = 0; mt < 4; ++mt)
#pragma unroll
        for (int nt = 0; nt < 4; ++nt) acc[mt][nt] = (f32x4){0.f, 0.f, 0.f, 0.f};

    __syncthreads();

    int nbase = wid << 6;
#pragma unroll
    for (int nt = 0; nt < 4; ++nt) {
        int pp = nbase + (nt << 4) + nl;
#pragma unroll
        for (int kh = 0; kh < 2; ++kh) {
            int m = kh * 4 + kg;
            short8 bf = *(const short8*)&xb[(pp << 6) + ((m ^ (pp & 7)) << 3)];
#pragma unroll
            for (int mt = 0; mt < 4; ++mt)
                acc[mt][nt] = __builtin_amdgcn_mfma_f32_16x16x32_bf16(
                    af[mt * 2 + kh], bf, acc[mt][nt], 0, 0, 0);
        }
    }

    __syncthreads();

    float s_[16], q_[16];
#pragma unroll
    for (int i = 0; i < 16; ++i) { s_[i] = 0.f; q_[i] = 0.f; }

#pragma unroll
    for (int mt = 0; mt < 4; ++mt) {
        int c = (mt << 4) + (kg << 2);
        float b0 = brs[c], b1 = brs[c + 1], b2v = brs[c + 2], b3 = brs[c + 3];
        int chunk = c >> 3;
#pragma unroll
        for (int nt = 0; nt < 4; ++nt) {
            int pp = nbase + (nt << 4) + nl;
            f32x4 a = acc[mt][nt];
            float v0 = a[0] + b0, v1 = a[1] + b1, v2 = a[2] + b2v, v3 = a[3] + b3;
            s_[mt * 4 + 0] += v0; q_[mt * 4 + 0] += v0 * v0;
            s_[mt * 4 + 1] += v1; q_[mt * 4 + 1] += v1 * v1;
            s_[mt * 4 + 2] += v2; q_[mt * 4 + 2] += v2 * v2;
            s_[mt * 4 + 3] += v3; q_[mt * 4 + 3] += v3 * v3;
            unsigned lo = (unsigned)f2bf(v0) | ((unsigned)f2bf(v1) << 16);
            unsigned hi = (unsigned)f2bf(v2) | ((unsigned)f2bf(v3) << 16);
            unsigned* dst = (unsigned*)&xb[(pp << 6) + ((chunk ^ (pp & 7)) << 3) + ((kg & 1) << 2)];
            dst[0] = lo;
            dst[1] = hi;
        }
    }

#pragma unroll
    for (int i = 0; i < 16; ++i) {
#pragma unroll
        for (int m = 1; m <= 8; m <<= 1) {
            s_[i] += __shfl_xor(s_[i], m, 64);
            q_[i] += __shfl_xor(q_[i], m, 64);
        }
    }
    if (nl == 0) {
#pragma unroll
        for (int i = 0; i < 16; ++i) {
            int c = ((i >> 2) << 4) + (kg << 2) + (i & 3);
            atomicAdd(&ls[c], s_[i]);
            atomicAdd(&ls[64 + c], q_[i]);
        }
    }
    __syncthreads();
    if (tid < 128) atomicAdd(&stats[tid], ls[tid]);

    uint4* rp = (uint4*)(rb + ((size_t)(pid0 + p) << 6));
#pragma unroll
    for (int m = 0; m < 8; ++m)
        rp[m] = *(const uint4*)&xb[(p << 6) + ((m ^ (p & 7)) << 3)];
}

// K34 v2: fused involution+softplus+conv with CONV SPLIT INTO TWO 32-CH
// K-HALVES so zt holds only 32ch (20.7KB) -> total LDS ~52KB -> 3 blocks/CU.
// acc[16] persists across halves; conv-A overlaps stage(4) DMA.
// zt swizzle (4 chunks): s = cg ^ ((p>>1)&3)  -> conflict-free write & read.
__global__ __launch_bounds__(256) void k34_fused(
    const float* __restrict__ x, const unsigned short* __restrict__ rb,
    const float* __restrict__ stats, const float* __restrict__ gamma,
    const float* __restrict__ beta, const unsigned short* __restrict__ wtr2,
    const float* __restrict__ bspan, const unsigned short* __restrict__ wtr,
    const float* __restrict__ b2, float* __restrict__ out)
{
    __shared__ float xh0[8 * 20 * 24], xh1[8 * 20 * 24];  // 15,360B x2
    __shared__ unsigned short zt[324 * 32];               // 20,736B (kl overlays)
    __shared__ float a_s[C_], c_s[C_];

    int tid = threadIdx.x;
    if (tid < C_) {
        float inv_n = 1.f / (float)NPIX;
        float mu  = stats[tid] * inv_n;
        float var = stats[C_ + tid] * inv_n - mu * mu;
        float is  = rsqrtf(var + 1e-5f);
        float a   = gamma[tid] * is;
        a_s[tid] = a;
        c_s[tid] = beta[tid] - mu * a;
    }

    int blk = blockIdx.x;
    int b = blk >> 6, t = blk & 63;
    int h0 = (t >> 3) << 4, w0 = (t & 7) << 4;
    const float* xb_ = x + (((size_t)b * C_) << 14);
    const float* zgz = stats + 128;   // zeroed 16B region

    // halo DMA geometry: 960 items -> [8ch][20 rows][24 dw]
    int goff[4];
#pragma unroll
    for (int k = 0; k < 4; ++k) {
        int item = (k << 8) + tid;
        int c    = item / 120;
        int rem  = item - c * 120;
        int row  = rem / 6;
        int ii   = rem - row * 6;
        int gh   = h0 + row - 2;
        int gw   = w0 - 4 + (ii << 2);
        bool ok = (item < 960) && ((unsigned)gh < 128u) && ((unsigned)gw < 128u);
        goff[k] = ok ? ((c << 14) + (gh << 7) + gw) : -1;
    }

    auto stage = [&](int g, float* buf) {
#pragma unroll
        for (int k = 0; k < 4; ++k) {
            if (k < 3 || tid < 192) {
                int item = (k << 8) + tid;
                const float* src = (goff[k] >= 0) ? (xb_ + (g << 17) + goff[k]) : zgz;
                gl_lds16(src, buf + (item << 2));
            }
        }
    };

    int lane = tid & 63;
    int w_  = tid >> 6;
    int nl  = lane & 15;
    int kg  = lane >> 4;
    short8 af0 = ((const short8*)wtr2)[lane];
    short8 af1 = ((const short8*)wtr2)[64 + lane];

    stage(0, xh0);
    __syncthreads();               // a_s/c_s ready; stage0 landed
    stage(1, xh1);                 // flies under the kern phase

    // ---- kern for 324 halo pixels via MFMA ----
    float aa[2][8], cc[2][8];
#pragma unroll
    for (int kh = 0; kh < 2; ++kh) {
        int cb = (kh << 5) + (kg << 3);
#pragma unroll
        for (int e = 0; e < 8; ++e) { aa[kh][e] = a_s[cb + e]; cc[kh][e] = c_s[cb + e]; }
    }

    float* kl = (float*)zt;        // kern bounce, 11.7KB of zt
#pragma unroll
    for (int nt = 0; nt < 6; ++nt) {
        int col = (nt << 2) + w_;
        if (col < 21) {
            int hp = (col << 4) + nl;
            int py = hp / 18, px = hp - py * 18;
            int gh = h0 + py - 1, gw = w0 + px - 1;
            int ghc = min(max(gh, 0), 127), gwc = min(max(gw, 0), 127);
            int pid2 = (b << 14) + (ghc << 7) + gwc;
            f32x4 acc9 = (f32x4){0.f, 0.f, 0.f, 0.f};
#pragma unroll
            for (int kh = 0; kh < 2; ++kh) {
                uint4 rv = *(const uint4*)(rb + ((size_t)pid2 << 6) + (kh << 5) + (kg << 3));
                const unsigned* ru = (const unsigned*)&rv;
                unsigned po[4];
#pragma unroll
                for (int e2 = 0; e2 < 4; ++e2) {
                    float lo = __builtin_bit_cast(float, ru[e2] << 16);
                    float hi = __builtin_bit_cast(float, ru[e2] & 0xffff0000u);
                    float r0 = fmaxf(aa[kh][2 * e2]     * lo + cc[kh][2 * e2],     0.f);
                    float r1 = fmaxf(aa[kh][2 * e2 + 1] * hi + cc[kh][2 * e2 + 1], 0.f);
                    po[e2] = (unsigned)f2bf(r0) | ((unsigned)f2bf(r1) << 16);
                }
                short8 bfrag = __builtin_bit_cast(short8, *(uint4*)po);
                acc9 = __builtin_amdgcn_mfma_f32_16x16x32_bf16(
                    kh ? af1 : af0, bfrag, acc9, 0, 0, 0);
            }
#pragma unroll
            for (int e = 0; e < 4; ++e) {
                int rr = (kg << 2) + e;
                if (rr < 9) kl[hp * 9 + rr] = acc9[e];
            }
        }
    }
    __syncthreads();

    float kern0[9], kern1[9];
#pragma unroll
    for (int k = 0; k < 9; ++k) kern0[k] = kl[tid * 9 + k] + bspan[k];
    bool has2 = tid < 68;          // pixels 256..323
    if (has2) {
#pragma unroll
        for (int k = 0; k < 9; ++k) kern1[k] = kl[(256 + tid) * 9 + k] + bspan[k];
    }
    __syncthreads();               // kl reads done before zt overwritten

    // pixel decompositions for the z phase
    int py0 = tid / 18, px0 = tid - py0 * 18;
    bool ib0 = ((unsigned)(h0 + py0 - 1) < 128u) && ((unsigned)(w0 + px0 - 1) < 128u);
    int hp1 = 256 + tid;
    int py1 = hp1 / 18, px1 = hp1 - py1 * 18;
    bool ib1 = has2 && ((unsigned)(h0 + py1 - 1) < 128u) && ((unsigned)(w0 + px1 - 1) < 128u);

    // z for one 8-channel group g into zt chunk g&3
    auto computeZ = [&](int g) {
        const float* xf = (g & 1) ? xh1 : xh0;
        int cgz = g & 3;
        unsigned pk[4];
        if (ib0) {
#pragma unroll
            for (int cp = 0; cp < 4; ++cp) {
                const float* p0 = xf + (cp * 2) * 480 + py0 * 24 + px0 + 2;
                const float* p1 = p0 + 480;
                float acc0 = 0.f, acc1 = 0.f;
#pragma unroll
                for (int i = 0; i < 3; ++i)
#pragma unroll
                    for (int j = 0; j < 3; ++j) {
                        float kv = kern0[i * 3 + j];
                        acc0 += kv * p0[i * 24 + j];
                        acc1 += kv * p1[i * 24 + j];
                    }
                pk[cp] = (unsigned)f2bf(softplus_fast(acc0))
                       | ((unsigned)f2bf(softplus_fast(acc1)) << 16);
            }
        } else {
#pragma unroll
            for (int cp = 0; cp < 4; ++cp) pk[cp] = 0u;
        }
        *(uint4*)&zt[(tid << 5) + ((cgz ^ ((tid >> 1) & 3)) << 3)] = *(uint4*)pk;

        if (has2) {
            if (ib1) {
#pragma unroll
                for (int cp = 0; cp < 4; ++cp) {
                    const float* p0 = xf + (cp * 2) * 480 + py1 * 24 + px1 + 2;
                    const float* p1 = p0 + 480;
                    float acc0 = 0.f, acc1 = 0.f;
#pragma unroll
                    for (int i = 0; i < 3; ++i)
#pragma unroll
                        for (int j = 0; j < 3; ++j) {
                            float kv = kern1[i * 3 + j];
                            acc0 += kv * p0[i * 24 + j];
                            acc1 += kv * p1[i * 24 + j];
                        }
                    pk[cp] = (unsigned)f2bf(softplus_fast(acc0))
                           | ((unsigned)f2bf(softplus_fast(acc1)) << 16);
                }
            } else {
#pragma unroll
                for (int cp = 0; cp < 4; ++cp) pk[cp] = 0u;
            }
            *(uint4*)&zt[(hp1 << 5) + ((cgz ^ ((hp1 >> 1) & 3)) << 3)] = *(uint4*)pk;
        }
    };

    f32x4 acc[16];
#pragma unroll
    for (int nt = 0; nt < 16; ++nt) acc[nt] = (f32x4){0.f, 0.f, 0.f, 0.f};

    const short8* wp = (const short8*)wtr;
    // conv accumulate one 32-ch half from zt
    auto convHalf = [&](int half) {
        short8 wfh[9];
#pragma unroll
        for (int f9 = 0; f9 < 9; ++f9)
            wfh[f9] = wp[(size_t)(w_ * 18 + f9 * 2 + half) * 64 + lane];
#pragma unroll
        for (int y = 0; y < 18; ++y) {
            short8 bf[3];
#pragma unroll
            for (int j = 0; j < 3; ++j) {
                int p = y * 18 + j + nl;
                bf[j] = *(const short8*)&zt[(p << 5) + ((kg ^ ((p >> 1) & 3)) << 3)];
            }
#pragma unroll
            for (int i = 0; i < 3; ++i) {
                int nt = y - i;
                if (nt >= 0 && nt < 16) {
#pragma unroll
                    for (int j = 0; j < 3; ++j)
                        acc[nt] = __builtin_amdgcn_mfma_f32_16x16x32_bf16(
                            wfh[i * 3 + j], bf[j], acc[nt], 0, 0, 0);
                }
            }
        }
    };

    // ---- phase A: z ch0-31 (groups 0-3), conv half 0 ----
#pragma unroll 1
    for (int g = 0; g < 4; ++g) {
        if (g >= 1) stage(g + 1, (g & 1) ? xh0 : xh1);   // stage 2,3,4
        computeZ(g);
        __syncthreads();
    }
    convHalf(0);                   // stage(4) DMA flies under this
    __syncthreads();               // zt reads done; stage4 landed

    // ---- phase B: z ch32-63 (groups 4-7), conv half 1 ----
#pragma unroll 1
    for (int g = 4; g < 8; ++g) {
        if (g < 7) stage(g + 1, (g & 1) ? xh0 : xh1);    // stage 5,6,7
        computeZ(g);
        __syncthreads();
    }
    convHalf(1);

    float bias[4];
#pragma unroll
    for (int r = 0; r < 4; ++r) bias[r] = b2[(w_ << 4) + (kg << 2) + r];

    size_t ob = ((size_t)b) << 20;
#pragma unroll
    for (int nt = 0; nt < 16; ++nt) {
        int h = h0 + nt;
#pragma unroll
        for (int r = 0; r < 4; ++r) {
            int o = (w_ << 4) + (kg << 2) + r;
            float v = acc[nt][r] + bias[r];
            out[ob + ((size_t)o << 14) + (h << 7) + w0 + nl] = softplus_fast(v);
        }
    }
}

extern "C" void kernel_launch(void* const* d_in, const int* in_sizes, int n_in,
                              void* d_out, int out_size, void* d_ws, size_t ws_size,
                              hipStream_t stream)
{
    const float* x   = (const float*)d_in[0];
    const float* wr  = (const float*)d_in[1];
    const float* br  = (const float*)d_in[2];
    const float* gam = (const float*)d_in[3];
    const float* bet = (const float*)d_in[4];
    const float* wsp = (const float*)d_in[5];
    const float* bsp = (const float*)d_in[6];
    const float* w2  = (const float*)d_in[7];
    const float* b2  = (const float*)d_in[8];
    float* out = (float*)d_out;

    // ws: rb bf16[NPIX*64] | wtr[4608*8] | wtr1[512*8] | wtr2[128*8]
    //     | stats f32[128] | zeros f32[128]
    unsigned short* rb   = (unsigned short*)d_ws;
    unsigned short* wtr  = rb + (size_t)NPIX * C_;
    unsigned short* wtr1 = wtr + 4608 * 8;
    unsigned short* wtr2 = wtr1 + 512 * 8;
    float* stats = (float*)(wtr2 + 128 * 8);

    k0_wtr<<<18, 256, 0, stream>>>(w2, wr, wsp, wtr, wtr1, wtr2, stats);
    k1_mfma<<<NPIX / 256, 256, 0, stream>>>(x, wtr1, br, rb, stats);
    k34_fused<<<NPIX / 256, 256, 0, stream>>>(x, rb, stats, gam, bet, wtr2, bsp,
                                              wtr, b2, out);
}

// Round 13
// 76.898 us; speedup vs baseline: 1.2909x; 1.2909x over previous
//
#include <hip/hip_runtime.h>
#include <math.h>

#define H_ 128
#define W_ 128
#define C_ 64
#define B_ 8
#define HW 16384          // H_*W_
#define NPIX (B_*HW)      // 131072

typedef __attribute__((ext_vector_type(8))) short short8;
typedef __attribute__((ext_vector_type(4))) float f32x4;

__device__ __forceinline__ float softplus_fast(float v) {
    return fmaxf(v, 0.f) + __logf(1.f + __expf(-fabsf(v)));
}

__device__ __forceinline__ unsigned short f2bf(float f) {
    unsigned u = __builtin_bit_cast(unsigned, f);
    unsigned r = (u + 0x7fffu + ((u >> 16) & 1u)) >> 16;
    return (unsigned short)r;
}

// async global->LDS, 16B per lane. LDS dest must be linear: base + lane*16.
__device__ __forceinline__ void gl_lds16(const float* g, float* l) {
    __builtin_amdgcn_global_load_lds(
        (const __attribute__((address_space(1))) void*)g,
        (__attribute__((address_space(3))) void*)l, 16, 0, 0);
}

// K0: (a) w2 -> bf16 A-frags (wtr); (b) w_reduce -> A-frags (wtr1);
//     (c) w_span -> 2 zero-padded A-frags (wtr2); (d) block 0 zeroes
//     stats[128] + zgz[128] (must run every call; stats accumulate).
__global__ __launch_bounds__(256) void k0_wtr(const float* __restrict__ w2,
                                              const float* __restrict__ wr,
                                              const float* __restrict__ wspan,
                                              unsigned short* __restrict__ wtr,
                                              unsigned short* __restrict__ wtr1,
                                              unsigned short* __restrict__ wtr2,
                                              float* __restrict__ stats)
{
    int t = blockIdx.x * 256 + threadIdx.x;
    if (t < 256) stats[t] = 0.f;            // stats[128] + zeros[128]
    if (t < 512) {
        int lane = t & 63, f = t >> 6;
        int mt = f >> 1, kh = f & 1;
        int o  = mt * 16 + (lane & 15);
        int c0 = kh * 32 + ((lane >> 4) << 3);
        uint4 pk;
        unsigned short* pv = (unsigned short*)&pk;
#pragma unroll
        for (int e = 0; e < 8; ++e)
            pv[e] = f2bf(wr[o * C_ + c0 + e]);
        *(uint4*)&wtr1[(size_t)t * 8] = pk;
    } else if (t < 640) {
        int tt = t - 512;
        int lane = tt & 63, kh = tt >> 6;
        int o  = lane & 15;
        int c0 = (kh << 5) + ((lane >> 4) << 3);
        uint4 pk;
        unsigned short* pv = (unsigned short*)&pk;
#pragma unroll
        for (int e = 0; e < 8; ++e)
            pv[e] = (o < 9) ? f2bf(wspan[o * C_ + c0 + e]) : (unsigned short)0;
        *(uint4*)&wtr2[(size_t)tt * 8] = pk;
    }
    if (t >= 4 * 18 * 64) return;
    int lane = t & 63;
    int f    = (t >> 6) % 18;
    int wv   = t / (18 * 64);
    int koff = f >> 1, ch = f & 1;
    int o = wv * 16 + (lane & 15);
    int cb = ch * 32 + ((lane >> 4) << 3);
    uint4 pk;
    unsigned short* pv = (unsigned short*)&pk;
#pragma unroll
    for (int e = 0; e < 8; ++e)
        pv[e] = f2bf(w2[(size_t)o * 576 + (size_t)(cb + e) * 9 + koff]);
    *(uint4*)&wtr[(size_t)t * 8] = pk;
}

// K1: r = W_reduce @ x + b_reduce via MFMA implicit GEMM; BN stats
// (sum/sumsq incl. bias, f32) folded in from the accumulators. Unchanged.
__global__ __launch_bounds__(256) void k1_mfma(
    const float* __restrict__ x, const unsigned short* __restrict__ wtr1,
    const float* __restrict__ br, unsigned short* __restrict__ rb,
    float* __restrict__ stats)
{
    __shared__ unsigned short xb[256 * 64];   // 32KB, chunk-XOR swizzled
    __shared__ float brs[C_];
    __shared__ float ls[128];
    int tid = threadIdx.x;
    int blk = blockIdx.x;
    int pid0 = blk << 8;
    int b    = pid0 >> 14;
    int rem0 = pid0 & (HW - 1);
    const float* xbase = x + (((size_t)b * C_) << 14) + rem0;

    if (tid < C_) brs[tid] = br[tid];
    if (tid < 128) ls[tid] = 0.f;

    int p = tid;
#pragma unroll
    for (int m = 0; m < 8; ++m) {
        float tmp[8];
#pragma unroll
        for (int e = 0; e < 8; ++e)
            tmp[e] = xbase[((size_t)(m * 8 + e) << 14) + p];
        unsigned pk[4];
#pragma unroll
        for (int e = 0; e < 4; ++e)
            pk[e] = (unsigned)f2bf(tmp[2 * e]) | ((unsigned)f2bf(tmp[2 * e + 1]) << 16);
        *(uint4*)&xb[(p << 6) + ((m ^ (p & 7)) << 3)] = *(uint4*)pk;
    }

    int wid = tid >> 6, lane = tid & 63;
    int nl  = lane & 15;
    int kg  = lane >> 4;

    short8 af[8];
    const short8* wp = (const short8*)wtr1;
#pragma unroll
    for (int f = 0; f < 8; ++f) af[f] = wp[f * 64 + lane];

    f32x4 acc[4][4];
#pragma unroll
    for (int mt = 0; mt < 4; ++mt)
#pragma unroll
        for (int nt = 0; nt < 4; ++nt) acc[mt][nt] = (f32x4){0.f, 0.f, 0.f, 0.f};

    __syncthreads();

    int nbase = wid << 6;
#pragma unroll
    for (int nt = 0; nt < 4; ++nt) {
        int pp = nbase + (nt << 4) + nl;
#pragma unroll
        for (int kh = 0; kh < 2; ++kh) {
            int m = kh * 4 + kg;
            short8 bf = *(const short8*)&xb[(pp << 6) + ((m ^ (pp & 7)) << 3)];
#pragma unroll
            for (int mt = 0; mt < 4; ++mt)
                acc[mt][nt] = __builtin_amdgcn_mfma_f32_16x16x32_bf16(
                    af[mt * 2 + kh], bf, acc[mt][nt], 0, 0, 0);
        }
    }

    __syncthreads();

    float s_[16], q_[16];
#pragma unroll
    for (int i = 0; i < 16; ++i) { s_[i] = 0.f; q_[i] = 0.f; }

#pragma unroll
    for (int mt = 0; mt < 4; ++mt) {
        int c = (mt << 4) + (kg << 2);
        float b0 = brs[c], b1 = brs[c + 1], b2v = brs[c + 2], b3 = brs[c + 3];
        int chunk = c >> 3;
#pragma unroll
        for (int nt = 0; nt < 4; ++nt) {
            int pp = nbase + (nt << 4) + nl;
            f32x4 a = acc[mt][nt];
            float v0 = a[0] + b0, v1 = a[1] + b1, v2 = a[2] + b2v, v3 = a[3] + b3;
            s_[mt * 4 + 0] += v0; q_[mt * 4 + 0] += v0 * v0;
            s_[mt * 4 + 1] += v1; q_[mt * 4 + 1] += v1 * v1;
            s_[mt * 4 + 2] += v2; q_[mt * 4 + 2] += v2 * v2;
            s_[mt * 4 + 3] += v3; q_[mt * 4 + 3] += v3 * v3;
            unsigned lo = (unsigned)f2bf(v0) | ((unsigned)f2bf(v1) << 16);
            unsigned hi = (unsigned)f2bf(v2) | ((unsigned)f2bf(v3) << 16);
            unsigned* dst = (unsigned*)&xb[(pp << 6) + ((chunk ^ (pp & 7)) << 3) + ((kg & 1) << 2)];
            dst[0] = lo;
            dst[1] = hi;
        }
    }

#pragma unroll
    for (int i = 0; i < 16; ++i) {
#pragma unroll
        for (int m = 1; m <= 8; m <<= 1) {
            s_[i] += __shfl_xor(s_[i], m, 64);
            q_[i] += __shfl_xor(q_[i], m, 64);
        }
    }
    if (nl == 0) {
#pragma unroll
        for (int i = 0; i < 16; ++i) {
            int c = ((i >> 2) << 4) + (kg << 2) + (i & 3);
            atomicAdd(&ls[c], s_[i]);
            atomicAdd(&ls[64 + c], q_[i]);
        }
    }
    __syncthreads();
    if (tid < 128) atomicAdd(&stats[tid], ls[tid]);

    uint4* rp = (uint4*)(rb + ((size_t)(pid0 + p) << 6));
#pragma unroll
    for (int m = 0; m < 8; ++m)
        rp[m] = *(const uint4*)&xb[(p << 6) + ((m ^ (p & 7)) << 3)];
}

// K34 v3: 512-thread blocks (8 waves) on the v1 LDS layout -> 2 blocks/CU
// = 4 waves/SIMD (double v1). Conv split per-wave: wave (og=w&3, yh=w>>2)
// owns 16 out-ch x 8 out-rows; two kh-passes keep VGPR <= 128.
__global__ __launch_bounds__(512, 4) void k34_fused(
    const float* __restrict__ x, const unsigned short* __restrict__ rb,
    const float* __restrict__ stats, const float* __restrict__ gamma,
    const float* __restrict__ beta, const unsigned short* __restrict__ wtr2,
    const float* __restrict__ bspan, const unsigned short* __restrict__ wtr,
    const float* __restrict__ b2, float* __restrict__ out)
{
    __shared__ float xh0[8 * 20 * 24], xh1[8 * 20 * 24];  // 15,360B x2
    __shared__ unsigned short zt[324 * 64];               // 41,472B (kl overlays)
    __shared__ float a_s[C_], c_s[C_];

    int tid = threadIdx.x;
    if (tid < C_) {
        float inv_n = 1.f / (float)NPIX;
        float mu  = stats[tid] * inv_n;
        float var = stats[C_ + tid] * inv_n - mu * mu;
        float is  = rsqrtf(var + 1e-5f);
        float a   = gamma[tid] * is;
        a_s[tid] = a;
        c_s[tid] = beta[tid] - mu * a;
    }

    int blk = blockIdx.x;
    int b = blk >> 6, t = blk & 63;
    int h0 = (t >> 3) << 4, w0 = (t & 7) << 4;
    const float* xb_ = x + (((size_t)b * C_) << 14);
    const float* zgz = stats + 128;   // zeroed 16B region

    // halo DMA geometry: 960 items -> [8ch][20 rows][24 dw]; 512 threads
    int goff[2];
#pragma unroll
    for (int k = 0; k < 2; ++k) {
        int item = (k << 9) + tid;
        int c    = item / 120;
        int rem  = item - c * 120;
        int row  = rem / 6;
        int ii   = rem - row * 6;
        int gh   = h0 + row - 2;
        int gw   = w0 - 4 + (ii << 2);
        bool ok = (item < 960) && ((unsigned)gh < 128u) && ((unsigned)gw < 128u);
        goff[k] = ok ? ((c << 14) + (gh << 7) + gw) : -1;
    }

    auto stage = [&](int g, float* buf) {
#pragma unroll
        for (int k = 0; k < 2; ++k) {
            if (k == 0 || tid < 448) {
                int item = (k << 9) + tid;
                const float* src = (goff[k] >= 0) ? (xb_ + (g << 17) + goff[k]) : zgz;
                gl_lds16(src, buf + (item << 2));
            }
        }
    };

    int lane = tid & 63;
    int w_  = tid >> 6;            // wave 0..7
    int nl  = lane & 15;
    int kg  = lane >> 4;
    short8 af0 = ((const short8*)wtr2)[lane];
    short8 af1 = ((const short8*)wtr2)[64 + lane];

    stage(0, xh0);
    __syncthreads();               // a_s/c_s ready; stage0 landed
    stage(1, xh1);                 // flies under the kern phase

    // ---- kern for 324(336) halo pixels via MFMA; waves 0-6 take 3 cols ----
    float aa[2][8], cc[2][8];
#pragma unroll
    for (int kh = 0; kh < 2; ++kh) {
        int cb = (kh << 5) + (kg << 3);
#pragma unroll
        for (int e = 0; e < 8; ++e) { aa[kh][e] = a_s[cb + e]; cc[kh][e] = c_s[cb + e]; }
    }

    float* kl = (float*)zt;        // kern bounce, ~12.1KB of zt
#pragma unroll
    for (int i3 = 0; i3 < 3; ++i3) {
        int col = w_ * 3 + i3;
        if (col < 21) {
            int hp = (col << 4) + nl;
            int py = hp / 18, px = hp - py * 18;
            int gh = h0 + py - 1, gw = w0 + px - 1;
            int ghc = min(max(gh, 0), 127), gwc = min(max(gw, 0), 127);
            int pid2 = (b << 14) + (ghc << 7) + gwc;
            f32x4 acc9 = (f32x4){0.f, 0.f, 0.f, 0.f};
#pragma unroll
            for (int kh = 0; kh < 2; ++kh) {
                uint4 rv = *(const uint4*)(rb + ((size_t)pid2 << 6) + (kh << 5) + (kg << 3));
                const unsigned* ru = (const unsigned*)&rv;
                unsigned po[4];
#pragma unroll
                for (int e2 = 0; e2 < 4; ++e2) {
                    float lo = __builtin_bit_cast(float, ru[e2] << 16);
                    float hi = __builtin_bit_cast(float, ru[e2] & 0xffff0000u);
                    float r0 = fmaxf(aa[kh][2 * e2]     * lo + cc[kh][2 * e2],     0.f);
                    float r1 = fmaxf(aa[kh][2 * e2 + 1] * hi + cc[kh][2 * e2 + 1], 0.f);
                    po[e2] = (unsigned)f2bf(r0) | ((unsigned)f2bf(r1) << 16);
                }
                short8 bfrag = __builtin_bit_cast(short8, *(uint4*)po);
                acc9 = __builtin_amdgcn_mfma_f32_16x16x32_bf16(
                    kh ? af1 : af0, bfrag, acc9, 0, 0, 0);
            }
#pragma unroll
            for (int e = 0; e < 4; ++e) {
                int rr = (kg << 2) + e;
                if (rr < 9) kl[hp * 9 + rr] = acc9[e];
            }
        }
    }
    __syncthreads();

    bool hasPix = tid < 324;
    float kern0[9];
    if (hasPix) {
#pragma unroll
        for (int k = 0; k < 9; ++k) kern0[k] = kl[tid * 9 + k] + bspan[k];
    }
    __syncthreads();               // kl reads done before zt overwritten

    int py0 = tid / 18, px0 = tid - py0 * 18;
    bool ib0 = hasPix && ((unsigned)(h0 + py0 - 1) < 128u) && ((unsigned)(w0 + px0 - 1) < 128u);

    // ---- z for 324 pixels, 8 groups of 8 channels, depth-1 DMA pipeline ----
#pragma unroll 1
    for (int g = 0; g < 8; ++g) {
        if (g >= 1 && g < 7) stage(g + 1, (g & 1) ? xh0 : xh1);
        const float* xf = (g & 1) ? xh1 : xh0;
        if (hasPix) {
            unsigned pk[4];
            if (ib0) {
#pragma unroll
                for (int cp = 0; cp < 4; ++cp) {
                    const float* p0 = xf + (cp * 2) * 480 + py0 * 24 + px0 + 2;
                    const float* p1 = p0 + 480;
                    float acc0 = 0.f, acc1 = 0.f;
#pragma unroll
                    for (int i = 0; i < 3; ++i)
#pragma unroll
                        for (int j = 0; j < 3; ++j) {
                            float kv = kern0[i * 3 + j];
                            acc0 += kv * p0[i * 24 + j];
                            acc1 += kv * p1[i * 24 + j];
                        }
                    pk[cp] = (unsigned)f2bf(softplus_fast(acc0))
                           | ((unsigned)f2bf(softplus_fast(acc1)) << 16);
                }
            } else {
#pragma unroll
                for (int cp = 0; cp < 4; ++cp) pk[cp] = 0u;
            }
            *(uint4*)&zt[(tid << 6) + ((g ^ (tid & 7)) << 3)] = *(uint4*)pk;
        }
        __syncthreads();
    }

    // ---- dense 3x3 conv via MFMA; wave owns (og, yh); two kh-passes ----
    int og = w_ & 3, yh = w_ >> 2;
    int ybase = yh << 3;           // first output row of this wave
    f32x4 acc[8];
#pragma unroll
    for (int nt = 0; nt < 8; ++nt) acc[nt] = (f32x4){0.f, 0.f, 0.f, 0.f};

    const short8* wp = (const short8*)wtr;
#pragma unroll
    for (int kh = 0; kh < 2; ++kh) {
        short8 wfh[9];
#pragma unroll
        for (int f9 = 0; f9 < 9; ++f9)
            wfh[f9] = wp[(size_t)(og * 18 + f9 * 2 + kh) * 64 + lane];
        int cg = kh * 4 + kg;
#pragma unroll
        for (int yy = 0; yy < 10; ++yy) {
            int y = ybase + yy;
            short8 bf[3];
#pragma unroll
            for (int j = 0; j < 3; ++j) {
                int p = y * 18 + j + nl;
                bf[j] = *(const short8*)&zt[(p << 6) + ((cg ^ (p & 7)) << 3)];
            }
#pragma unroll
            for (int i = 0; i < 3; ++i) {
                int nt = yy - i;
                if (nt >= 0 && nt < 8) {
#pragma unroll
                    for (int j = 0; j < 3; ++j)
                        acc[nt] = __builtin_amdgcn_mfma_f32_16x16x32_bf16(
                            wfh[i * 3 + j], bf[j], acc[nt], 0, 0, 0);
                }
            }
        }
    }

    float bias[4];
#pragma unroll
    for (int r = 0; r < 4; ++r) bias[r] = b2[(og << 4) + (kg << 2) + r];

    size_t ob = ((size_t)b) << 20;
#pragma unroll
    for (int nt = 0; nt < 8; ++nt) {
        int h = h0 + ybase + nt;
#pragma unroll
        for (int r = 0; r < 4; ++r) {
            int o = (og << 4) + (kg << 2) + r;
            float v = acc[nt][r] + bias[r];
            out[ob + ((size_t)o << 14) + (h << 7) + w0 + nl] = softplus_fast(v);
        }
    }
}

extern "C" void kernel_launch(void* const* d_in, const int* in_sizes, int n_in,
                              void* d_out, int out_size, void* d_ws, size_t ws_size,
                              hipStream_t stream)
{
    const float* x   = (const float*)d_in[0];
    const float* wr  = (const float*)d_in[1];
    const float* br  = (const float*)d_in[2];
    const float* gam = (const float*)d_in[3];
    const float* bet = (const float*)d_in[4];
    const float* wsp = (const float*)d_in[5];
    const float* bsp = (const float*)d_in[6];
    const float* w2  = (const float*)d_in[7];
    const float* b2  = (const float*)d_in[8];
    float* out = (float*)d_out;

    // ws: rb bf16[NPIX*64] | wtr[4608*8] | wtr1[512*8] | wtr2[128*8]
    //     | stats f32[128] | zeros f32[128]
    unsigned short* rb   = (unsigned short*)d_ws;
    unsigned short* wtr  = rb + (size_t)NPIX * C_;
    unsigned short* wtr1 = wtr + 4608 * 8;
    unsigned short* wtr2 = wtr1 + 512 * 8;
    float* stats = (float*)(wtr2 + 128 * 8);

    k0_wtr<<<18, 256, 0, stream>>>(w2, wr, wsp, wtr, wtr1, wtr2, stats);
    k1_mfma<<<NPIX / 256, 256, 0, stream>>>(x, wtr1, br, rb, stats);
    k34_fused<<<NPIX / 256, 512, 0, stream>>>(x, rb, stats, gam, bet, wtr2, bsp,
                                              wtr, b2, out);
}